// Round 1
// baseline (459.215 us; speedup 1.0000x reference)
//
#include <hip/hip_runtime.h>
#include <stdint.h>

typedef unsigned short u16;
typedef __attribute__((ext_vector_type(8))) short short8;
typedef __attribute__((ext_vector_type(4))) float f32x4;

#define NTOK 256
#define KGU  5120
#define HCOL 27648
#define NPD  2560
#define KD   27648
#define SPLITK 16
#define KCH  1728            // 27648/16
#define PELEMS (NTOK*NPD)    // 655360

__device__ __forceinline__ void gl_lds16(const void* gp, void* lp) {
  __builtin_amdgcn_global_load_lds((const __attribute__((address_space(1))) uint32_t*)gp,
                                   (__attribute__((address_space(3))) uint32_t*)lp, 16, 0, 0);
}
__device__ __forceinline__ uint32_t f2bf(float x) {  // RNE f32->bf16 bits
  uint32_t b = __float_as_uint(x);
  return (b + 0x7fffu + ((b >> 16) & 1u)) >> 16;
}
__device__ __forceinline__ uint32_t pk2(float lo, float hi) { return f2bf(lo) | (f2bf(hi) << 16); }
__device__ __forceinline__ void pack8_store(u16* dst, const float4& a, const float4& b) {
  uint4 v;
  v.x = pk2(a.x, a.y); v.y = pk2(a.z, a.w); v.z = pk2(b.x, b.y); v.w = pk2(b.z, b.w);
  *(uint4*)dst = v;
}
__device__ __forceinline__ float silu(float x) {
  return x * __builtin_amdgcn_rcpf(1.f + __expf(-x));
}

// ---------------- kernel 0: x fp32 -> bf16 ----------------
__global__ __launch_bounds__(256) void k_cvt(const float* __restrict__ X, u16* __restrict__ Xb) {
  int i = (blockIdx.x * 256 + threadIdx.x) * 8;
  float4 a = *(const float4*)(X + i);
  float4 b = *(const float4*)(X + i + 4);
  pack8_store(Xb + i, a, b);
}

// tiny per-channel MLP, 4 gate + 4 up values at once (shared const reads)
__device__ __forceinline__ void qrun4x2(
    const float* pg, const float* pu,
    const float4* __restrict__ cg0, const float* __restrict__ cg1, float b2g0, float b2g1,
    const float4* __restrict__ cu0, const float* __restrict__ cu1, float b2u0, float b2u1,
    float* hout) {
  float sg[4], cg[4], su[4], cu[4], og0[4], og1[4], ou0[4], ou1[4];
#pragma unroll
  for (int e = 0; e < 4; ++e) {
    sg[e] = __sinf(pg[e]); cg[e] = __cosf(pg[e]);
    su[e] = __sinf(pu[e]); cu[e] = __cosf(pu[e]);
    og0[e] = b2g0; og1[e] = b2g1; ou0[e] = b2u0; ou1[e] = b2u1;
  }
#pragma unroll 4
  for (int m = 0; m < 32; ++m) {
    float4 kg = cg0[m]; float kg1 = cg1[m];
    float4 ku = cu0[m]; float ku1 = cu1[m];
#pragma unroll
    for (int e = 0; e < 4; ++e) {
      float hg = fmaxf(fmaf(sg[e], kg.x, fmaf(cg[e], kg.y, kg.z)), 0.f);
      og0[e] = fmaf(hg, kg.w, og0[e]);
      og1[e] = fmaf(hg, kg1,  og1[e]);
      float hu = fmaxf(fmaf(su[e], ku.x, fmaf(cu[e], ku.y, ku.z)), 0.f);
      ou0[e] = fmaf(hu, ku.w, ou0[e]);
      ou1[e] = fmaf(hu, ku1,  ou1[e]);
    }
  }
#pragma unroll
  for (int e = 0; e < 4; ++e) {
    hout[2*e]   = silu(og0[e]) * ou0[e];
    hout[2*e+1] = silu(og1[e]) * ou1[e];
  }
}

// ---------------- kernel 1: fused gate+up GEMM + QRUN epilogue -> h bf16 ----------------
// block: 256 thr (4 waves 2x2), tile 128(M) x [64 gate p-cols + 64 up p-cols], BK=64
__global__ __launch_bounds__(256, 2)
void k_gateup(const u16* __restrict__ X,
              const float* __restrict__ Wg, const float* __restrict__ bg,
              const float* __restrict__ W1g, const float* __restrict__ b1g,
              const float* __restrict__ W2g, const float* __restrict__ b2g,
              const float* __restrict__ Wu, const float* __restrict__ bu,
              const float* __restrict__ W1u, const float* __restrict__ b1u,
              const float* __restrict__ W2u, const float* __restrict__ b2u,
              u16* __restrict__ H) {
  __shared__ __align__(16) u16 smem[32768];   // 2 bufs x (A[128][64] + B[128][64]) bf16 = 64KB
  const int tid = threadIdx.x;
  const int lane = tid & 63;
  const int wid = tid >> 6;
  const int wm = wid >> 1, wn = wid & 1;
  const int j0 = blockIdx.x * 64;
  const int m0 = blockIdx.y * 128;

  // A staging: global_load_lds w/ source-pre-swizzle (LDS[r][s] = Aglob[r][s ^ (r&7)])
  const int arow = lane >> 3;                       // 0..7
  const int akoff = ((lane & 7) ^ arow) << 3;       // swizzled k-block
  const u16* Abase = X + (size_t)(m0 + arow) * KGU + akoff;

  // B staging: 2 thr/row, fp32 loads + cvt + swizzled ds_write_b128
  const int br = tid >> 1;                          // 0..127 tile row
  const int bh = tid & 1;
  const int grp = br >> 5;                          // 0:g 1:u 2:g 3:u
  const int jcol = j0 + ((grp >> 1) << 5) + (br & 31);
  const float* Wrow = ((grp & 1) ? Wu : Wg) + (size_t)jcol * KGU;

  f32x4 acc[4][4];
#pragma unroll
  for (int i = 0; i < 4; ++i)
#pragma unroll
    for (int j = 0; j < 4; ++j) acc[i][j] = (f32x4)0.f;

  const int s_ = lane & 15, quad = lane >> 4;
  float4 breg[8];

  auto stage_a = [&](int buf, int kt) {
#pragma unroll
    for (int i = 0; i < 4; ++i) {
      int c = (wid << 2) | i;                       // 16 x 1KB chunks
      gl_lds16(Abase + (size_t)(c << 3) * KGU + kt, &smem[buf * 16384 + (c << 9)]);
    }
  };
  auto stage_b_load = [&](int kt) {
#pragma unroll
    for (int kbi = 0; kbi < 4; ++kbi) {
      int kf = (((bh << 2) | kbi) << 3);
      breg[2*kbi]   = *(const float4*)(Wrow + kt + kf);
      breg[2*kbi+1] = *(const float4*)(Wrow + kt + kf + 4);
    }
  };
  auto stage_b_write = [&](int buf) {
#pragma unroll
    for (int kbi = 0; kbi < 4; ++kbi) {
      int kb = (bh << 2) | kbi;
      int slot = kb ^ (br & 7);
      pack8_store(&smem[buf * 16384 + 8192 + br * 64 + (slot << 3)], breg[2*kbi], breg[2*kbi+1]);
    }
  };
  auto compute = [&](int buf) {
    const u16* la = &smem[buf * 16384];
    const u16* lb = &smem[buf * 16384 + 8192];
#pragma unroll
    for (int kk = 0; kk < 2; ++kk) {
      short8 af[4], bfr[4];
#pragma unroll
      for (int mi = 0; mi < 4; ++mi) {
        int row = wm * 64 + mi * 16 + s_;
        int slot = (kk * 4 + quad) ^ (row & 7);
        af[mi] = *(const short8*)&la[row * 64 + (slot << 3)];
      }
#pragma unroll
      for (int ni = 0; ni < 4; ++ni) {
        int row = wn * 64 + ni * 16 + s_;
        int slot = (kk * 4 + quad) ^ (row & 7);
        bfr[ni] = *(const short8*)&lb[row * 64 + (slot << 3)];
      }
#pragma unroll
      for (int mi = 0; mi < 4; ++mi)
#pragma unroll
        for (int ni = 0; ni < 4; ++ni)
          acc[mi][ni] = __builtin_amdgcn_mfma_f32_16x16x32_bf16(af[mi], bfr[ni], acc[mi][ni], 0, 0, 0);
    }
  };

  stage_a(0, 0);
  stage_b_load(0);
  stage_b_write(0);
  int cur = 0;
  for (int t = 1; t < 80; ++t) {
    __syncthreads();
    int kt = t << 6;
    stage_a(cur ^ 1, kt);
    stage_b_load(kt);
    compute(cur);
    stage_b_write(cur ^ 1);
    cur ^= 1;
  }
  __syncthreads();
  compute(cur);

  // MLP consts into (now free) LDS
  __syncthreads();
  float4* mcg0 = (float4*)smem;            // 32 x float4
  float*  mcg1 = (float*)(smem + 256);     // 32 x float
  float4* mcu0 = (float4*)(smem + 320);
  float*  mcu1 = (float*)(smem + 576);
  if (tid < 32) {
    const float* w = W1g + tid * 6;
    mcg0[tid] = make_float4(w[0]+w[2]+w[4], w[1]+w[3]+w[5], b1g[tid], W2g[tid]);
    mcg1[tid] = W2g[32 + tid];
    const float* w2 = W1u + tid * 6;
    mcu0[tid] = make_float4(w2[0]+w2[2]+w2[4], w2[1]+w2[3]+w2[5], b1u[tid], W2u[tid]);
    mcu1[tid] = W2u[32 + tid];
  }
  __syncthreads();
  const float b2g0 = b2g[0], b2g1v = b2g[1], b2u0 = b2u[0], b2u1v = b2u[1];
#pragma unroll
  for (int ni = 0; ni < 2; ++ni) {
    const int j = j0 + wn * 32 + ni * 16 + s_;
    const float bpg = bg[j], bpu = bu[j];
#pragma unroll
    for (int mi = 0; mi < 4; ++mi) {
      float pg[4], pu[4], hv[8];
#pragma unroll
      for (int e = 0; e < 4; ++e) {
        pg[e] = acc[mi][ni][e] + bpg;
        pu[e] = acc[mi][ni + 2][e] + bpu;
      }
      qrun4x2(pg, pu, mcg0, mcg1, b2g0, b2g1v, mcu0, mcu1, b2u0, b2u1v, hv);
      const int mrow = m0 + wm * 64 + mi * 16 + (quad << 2);
#pragma unroll
      for (int e = 0; e < 4; ++e)
        *(uint32_t*)&H[(size_t)(mrow + e) * HCOL + 2 * j] = pk2(hv[2*e], hv[2*e+1]);
    }
  }
}

// ---------------- kernel 2: down GEMM (split-K) -> fp32 partials ----------------
// block: 256 thr (4 waves, M-split), tile 256(M) x 64(N), BK=32, K-chunk 1728
__global__ __launch_bounds__(256, 2)
void k_down(const u16* __restrict__ Hb, const float* __restrict__ Wd, float* __restrict__ P) {
  __shared__ __align__(16) u16 smem[20480];   // 2 bufs x (A[256][32] + B[64][32]) = 40KB
  const int tid = threadIdx.x, lane = tid & 63, wid = tid >> 6;
  const int n0 = blockIdx.x * 64;
  const int kc = blockIdx.y * KCH;

  const int arow = lane >> 2;                        // 0..15
  const int akoff = ((lane & 3) ^ (arow & 3)) << 3;
  const u16* Abase = Hb + (size_t)arow * KD + kc + akoff;

  const int brr = tid >> 2, tq = tid & 3;            // 4 thr/row
  const float* Wrow = Wd + (size_t)(n0 + brr) * KD + kc;
  const int bslot = tq ^ (brr & 3);

  f32x4 acc[4][4];
#pragma unroll
  for (int i = 0; i < 4; ++i)
#pragma unroll
    for (int j = 0; j < 4; ++j) acc[i][j] = (f32x4)0.f;

  const int s_ = lane & 15, quad = lane >> 4;
  float4 breg[2];

  auto stage_a = [&](int buf, int kt) {
#pragma unroll
    for (int i = 0; i < 4; ++i) {
      int c = (wid << 2) | i;                        // 16 x 1KB chunks (16 rows each)
      gl_lds16(Abase + (size_t)(c << 4) * KD + kt, &smem[buf * 10240 + (c << 9)]);
    }
  };
  auto stage_b_load = [&](int kt) {
    breg[0] = *(const float4*)(Wrow + kt + (tq << 3));
    breg[1] = *(const float4*)(Wrow + kt + (tq << 3) + 4);
  };
  auto stage_b_write = [&](int buf) {
    pack8_store(&smem[buf * 10240 + 8192 + brr * 32 + (bslot << 3)], breg[0], breg[1]);
  };
  auto compute = [&](int buf) {
    const u16* la = &smem[buf * 10240];
    const u16* lb = &smem[buf * 10240 + 8192];
    short8 af[4], bfr[4];
#pragma unroll
    for (int mi = 0; mi < 4; ++mi) {
      int row = wid * 64 + mi * 16 + s_;
      int slot = quad ^ (row & 3);
      af[mi] = *(const short8*)&la[row * 32 + (slot << 3)];
    }
#pragma unroll
    for (int ni = 0; ni < 4; ++ni) {
      int row = ni * 16 + s_;
      int slot = quad ^ (row & 3);
      bfr[ni] = *(const short8*)&lb[row * 32 + (slot << 3)];
    }
#pragma unroll
    for (int mi = 0; mi < 4; ++mi)
#pragma unroll
      for (int ni = 0; ni < 4; ++ni)
        acc[mi][ni] = __builtin_amdgcn_mfma_f32_16x16x32_bf16(af[mi], bfr[ni], acc[mi][ni], 0, 0, 0);
  };

  stage_a(0, 0); stage_b_load(0); stage_b_write(0);
  int cur = 0;
  for (int t = 1; t < 54; ++t) {
    __syncthreads();
    int kt = t << 5;
    stage_a(cur ^ 1, kt);
    stage_b_load(kt);
    compute(cur);
    stage_b_write(cur ^ 1);
    cur ^= 1;
  }
  __syncthreads();
  compute(cur);

  const size_t pb = (size_t)blockIdx.y * PELEMS;
#pragma unroll
  for (int mi = 0; mi < 4; ++mi) {
    int mrow = wid * 64 + mi * 16 + (quad << 2);
#pragma unroll
    for (int ni = 0; ni < 4; ++ni) {
      int n = n0 + ni * 16 + s_;
#pragma unroll
      for (int e = 0; e < 4; ++e)
        P[pb + (size_t)(mrow + e) * NPD + n] = acc[mi][ni][e];
    }
  }
}

// ---------------- kernel 3: reduce partials + QRUN-d epilogue -> out fp32 ----------------
__global__ __launch_bounds__(256) void k_fin(const float* __restrict__ P, const float* __restrict__ bd,
    const float* __restrict__ W1d, const float* __restrict__ b1d, const float* __restrict__ W2d,
    const float* __restrict__ b2d, float* __restrict__ out) {
  __shared__ float4 mc0[32];
  __shared__ float mc1[32];
  const int tid = threadIdx.x;
  if (tid < 32) {
    const float* w = W1d + tid * 6;
    mc0[tid] = make_float4(w[0]+w[2]+w[4], w[1]+w[3]+w[5], b1d[tid], W2d[tid]);
    mc1[tid] = W2d[32 + tid];
  }
  __syncthreads();
  const int idx = blockIdx.x * 256 + tid;          // < 655360
  const int m = idx / NPD, j = idx - m * NPD;
  float p = bd[j];
#pragma unroll
  for (int sk = 0; sk < SPLITK; ++sk) p += P[(size_t)sk * PELEMS + idx];
  float s = __sinf(p), c = __cosf(p);
  float o0 = b2d[0], o1 = b2d[1];
#pragma unroll 4
  for (int mm = 0; mm < 32; ++mm) {
    float4 k = mc0[mm];
    float hh = fmaxf(fmaf(s, k.x, fmaf(c, k.y, k.z)), 0.f);
    o0 = fmaf(hh, k.w, o0);
    o1 = fmaf(hh, mc1[mm], o1);
  }
  *(float2*)&out[(size_t)m * 5120 + 2 * j] = make_float2(o0, o1);
}

extern "C" void kernel_launch(void* const* d_in, const int* in_sizes, int n_in,
                              void* d_out, int out_size, void* d_ws, size_t ws_size,
                              hipStream_t stream) {
  const float* x   = (const float*)d_in[0];
  const float* Wg  = (const float*)d_in[1];
  const float* bg  = (const float*)d_in[2];
  const float* W1g = (const float*)d_in[3];
  const float* b1g = (const float*)d_in[4];
  const float* W2g = (const float*)d_in[5];
  const float* b2g = (const float*)d_in[6];
  const float* Wu  = (const float*)d_in[7];
  const float* bu  = (const float*)d_in[8];
  const float* W1u = (const float*)d_in[9];
  const float* b1u = (const float*)d_in[10];
  const float* W2u = (const float*)d_in[11];
  const float* b2u = (const float*)d_in[12];
  const float* Wd  = (const float*)d_in[13];
  const float* bd  = (const float*)d_in[14];
  const float* W1d = (const float*)d_in[15];
  const float* b1d = (const float*)d_in[16];
  const float* W2d = (const float*)d_in[17];
  const float* b2d = (const float*)d_in[18];
  char* ws = (char*)d_ws;
  u16*  xb = (u16*)ws;                    // 2,621,440 B
  u16*  hb = (u16*)(ws + 2621440);        // 14,155,776 B
  float* P = (float*)(ws + 16777216);     // 41,943,040 B
  if (ws_size < 58720256u) return;        // insufficient scratch -> loud failure

  k_cvt<<<dim3(640), dim3(256), 0, stream>>>(x, xb);
  k_gateup<<<dim3(216, 2), dim3(256), 0, stream>>>(xb, Wg, bg, W1g, b1g, W2g, b2g,
                                                   Wu, bu, W1u, b1u, W2u, b2u, hb);
  k_down<<<dim3(40, SPLITK), dim3(256), 0, stream>>>(hb, Wd, P);
  k_fin<<<dim3(2560), dim3(256), 0, stream>>>(P, bd, W1d, b1d, W2d, b2d, (float*)d_out);
}